// Round 3
// baseline (3579.271 us; speedup 1.0000x reference)
//
#include <hip/hip_runtime.h>

#define TT 8
#define NN 50000
#define FF 128
#define HH 64
#define CC 4
#define EE 800000
#define NB 782            // ceil(50000/64) buckets of 64 nodes

typedef unsigned short u16;

static __device__ __forceinline__ float bf2f(u16 u) {
    union { unsigned int i; float f; } v; v.i = ((unsigned int)u) << 16; return v.f;
}
static __device__ __forceinline__ u16 f2bf(float f) {
    union { float f; unsigned int u; } v; v.f = f;
    unsigned int u = v.u;
    unsigned int r = u + 0x7fffu + ((u >> 16) & 1u);   // round-to-nearest-even
    return (u16)(r >> 16);
}

// ---------------- histogram of edge destinations (in-degree, no self loop) ----------------
__global__ __launch_bounds__(256) void hist_kernel(const int* __restrict__ edges, int* __restrict__ cnt) {
    int bid = blockIdx.x;
    int t = bid & 7;
    int e = (bid >> 3) * 256 + threadIdx.x;
    if (e < EE) {
        int dst = edges[(t * 2 + 1) * EE + e];
        atomicAdd(&cnt[t * NN + dst], 1);
    }
}

// ---------------- per-bucket counts from cnt (no edge re-read) ----------------
__global__ __launch_bounds__(256) void bucket_cnt_kernel(const int* __restrict__ cnt, int* __restrict__ bcnt) {
    int t = blockIdx.y;
    int b = blockIdx.x * 256 + threadIdx.x;
    if (b >= NB) return;
    int s = 0;
    int base = b * 64;
    #pragma unroll 4
    for (int i = 0; i < 64; ++i) {
        int idx = base + i;
        if (idx < NN) s += cnt[t * NN + idx];
    }
    bcnt[t * NB + b] = s;
}

// ---------------- exclusive scan of 782 bucket counts per t ----------------
__global__ __launch_bounds__(1024) void bucket_scan_kernel(const int* __restrict__ bcnt,
                                                           int* __restrict__ bucketOff, int* __restrict__ cursor) {
    int t = blockIdx.x, tid = threadIdx.x;
    __shared__ int s[1024];
    int v = (tid < NB) ? bcnt[t * NB + tid] : 0;
    s[tid] = v; __syncthreads();
    for (int off = 1; off < 1024; off <<= 1) {
        int x = 0;
        if (tid >= off) x = s[tid - off];
        __syncthreads();
        s[tid] += x;
        __syncthreads();
    }
    if (tid < NB) {
        int excl = s[tid] - v;
        bucketOff[t * (NB + 1) + tid] = excl;
        cursor[t * NB + tid] = excl;
    }
    if (tid == 0) bucketOff[t * (NB + 1) + NB] = EE;
}

// ---------------- binning: append packed (src | dstlo<<16) per bucket ----------------
// 782 append streams per t (t pinned to one XCD): a 64B line fills with 16 records in
// ~1/64th of the pass -> short dirty-line lifetime -> full-line writebacks (vs the old
// 50000-stream CSR fill whose lines were evicted half-empty: 478MB written for 25.6MB).
__global__ __launch_bounds__(256) void bin_fill_kernel(const int* __restrict__ edges, int* __restrict__ cursor,
                                                       int* __restrict__ binned) {
    int bid = blockIdx.x;
    int t = bid & 7;
    int e = (bid >> 3) * 256 + threadIdx.x;
    if (e < EE) {
        int src = edges[(t * 2 + 0) * EE + e];
        int dst = edges[(t * 2 + 1) * EE + e];
        int b = dst >> 6;
        int p = atomicAdd(&cursor[t * NB + b], 1);
        binned[(size_t)t * EE + p] = src | ((dst & 63) << 16);
    }
}

// ---------------- y = (x @ Wg) * dinv  (per timestep), stored bf16 ----------------
__global__ __launch_bounds__(256) void xw_kernel(const float* __restrict__ x, const float* __restrict__ Wg,
                                                 const int* __restrict__ cnt, float* __restrict__ dinv,
                                                 u16* __restrict__ y) {
    int t = blockIdx.y;
    int row0 = blockIdx.x * 64;
    int tid = threadIdx.x;
    __shared__ __align__(16) float xs[64 * 132];
    __shared__ float ds[64];
    const float* xt = x + (size_t)t * NN * FF;
    // stage x tile (64 rows x 128 cols) with float4 loads (16B/lane)
    #pragma unroll
    for (int it = 0; it < 8; ++it) {
        int f = it * 256 + tid;          // float4 index: 64 rows x 32
        int r = f >> 5, k4 = f & 31;
        int row = row0 + r;
        float4 v = make_float4(0.f, 0.f, 0.f, 0.f);
        if (row < NN) v = *reinterpret_cast<const float4*>(&xt[(size_t)row * FF + k4 * 4]);
        *reinterpret_cast<float4*>(&xs[r * 132 + k4 * 4]) = v;
    }
    if (tid < 64) {
        int row = row0 + tid;
        float d = 0.f;
        if (row < NN) {
            d = rsqrtf(1.0f + (float)cnt[t * NN + row]);
            dinv[t * NN + row] = d;
        }
        ds[tid] = d;
    }
    __syncthreads();

    int c0 = (tid & 15) << 2;
    int r0 = (tid >> 4) << 2;
    const float* wgt = Wg + t * FF * HH;
    float s[4][4] = {};
    #pragma unroll 4
    for (int k0 = 0; k0 < 128; k0 += 4) {
        float4 xr[4], wr[4];
        #pragma unroll
        for (int j = 0; j < 4; ++j) xr[j] = *reinterpret_cast<const float4*>(&xs[(r0 + j) * 132 + k0]);
        #pragma unroll
        for (int j = 0; j < 4; ++j) wr[j] = *reinterpret_cast<const float4*>(&wgt[(k0 + j) * 64 + c0]);
        #pragma unroll
        for (int kk = 0; kk < 4; ++kk) {
            float wx = wr[kk].x, wy = wr[kk].y, wz = wr[kk].z, ww = wr[kk].w;
            #pragma unroll
            for (int r = 0; r < 4; ++r) {
                float xv = (kk == 0) ? xr[r].x : (kk == 1) ? xr[r].y : (kk == 2) ? xr[r].z : xr[r].w;
                s[r][0] += xv * wx;
                s[r][1] += xv * wy;
                s[r][2] += xv * wz;
                s[r][3] += xv * ww;
            }
        }
    }
    #pragma unroll
    for (int j = 0; j < 4; ++j) {
        int row = row0 + r0 + j;
        if (row < NN) {
            float dv = ds[r0 + j];
            ushort4 pk;
            pk.x = f2bf(s[j][0] * dv);
            pk.y = f2bf(s[j][1] * dv);
            pk.z = f2bf(s[j][2] * dv);
            pk.w = f2bf(s[j][3] * dv);
            *reinterpret_cast<ushort4*>(&y[((size_t)t * NN + row) * HH + c0]) = pk;
        }
    }
}

// ---------------- fused: bucket aggregate over T + relu-sum + MLP head + log_softmax ----------------
// one block per 64-node bucket; lane = feature. Edge gathers accumulate into LDS accT via
// ds_add_f32 (bank = lane%32, conflict-free); per-t relu-sum into padded accS; head runs
// entirely out of LDS -> no srclist/acc round-trips, no separate agg/head kernels.
__global__ __launch_bounds__(256) void agg_fused_kernel(const u16* __restrict__ y, const float* __restrict__ dinv,
                                                        const int* __restrict__ bucketOff, const int* __restrict__ binned,
                                                        const float* __restrict__ bg,
                                                        const float* __restrict__ W1, const float* __restrict__ b1,
                                                        const float* __restrict__ W2, const float* __restrict__ b2,
                                                        const float* __restrict__ W3, const float* __restrict__ b3,
                                                        float* __restrict__ out) {
    __shared__ float accT[64 * 64];    // per-t scatter target (atomic)
    __shared__ float accS[64 * 65];    // running relu-sum (padded: head reads stride-65)
    __shared__ float w1s[64 * 32], w2s[32 * 16], w3s[16 * 4], b1s[32], b2s[16], b3s[4];
    int tid = threadIdx.x;
    int b = blockIdx.x;
    int node0 = b * 64;

    for (int i = tid; i < 2048; i += 256) w1s[i] = W1[i];
    for (int i = tid; i < 512; i += 256) w2s[i] = W2[i];
    if (tid < 64) w3s[tid] = W3[tid];
    if (tid < 32) b1s[tid] = b1[tid];
    if (tid < 16) b2s[tid] = b2[tid];
    if (tid < 4)  b3s[tid] = b3[tid];
    for (int i = tid; i < 64 * 64; i += 256) accT[i] = 0.f;
    for (int i = tid; i < 64 * 65; i += 256) accS[i] = 0.f;
    __syncthreads();

    int w = tid >> 6, lane = tid & 63;

    for (int t = 0; t < TT; ++t) {
        const u16* yt = y + (size_t)t * NN * HH;
        int beg = bucketOff[t * (NB + 1) + b];
        int end = bucketOff[t * (NB + 1) + b + 1];
        const int* bl = binned + (size_t)t * EE;

        for (int base = beg + w * 64; base < end; base += 256) {
            int n = end - base; if (n > 64) n = 64;
            int p = (lane < n) ? bl[base + lane] : 0;
            if (n == 64) {
                #pragma unroll 8
                for (int k = 0; k < 64; ++k) {
                    int pk = __shfl(p, k);
                    int src = pk & 0xFFFF;
                    int d = pk >> 16;
                    float v = bf2f(yt[(size_t)src * HH + lane]);
                    atomicAdd(&accT[d * 64 + lane], v);
                }
            } else {
                for (int k = 0; k < n; ++k) {
                    int pk = __shfl(p, k);
                    int src = pk & 0xFFFF;
                    int d = pk >> 16;
                    float v = bf2f(yt[(size_t)src * HH + lane]);
                    atomicAdd(&accT[d * 64 + lane], v);
                }
            }
        }
        __syncthreads();
        // self-loop + dinv scale + bias + relu, accumulate; then re-zero accT
        #pragma unroll
        for (int i = 0; i < 16; ++i) {
            int n = w * 16 + i;
            int node = node0 + n;
            if (node < NN) {
                float s = accT[n * 64 + lane] + bf2f(yt[(size_t)node * HH + lane]);
                float v = dinv[t * NN + node] * s + bg[t * HH + lane];
                accS[n * 65 + lane] += fmaxf(v, 0.f);
            }
            accT[n * 64 + lane] = 0.f;
        }
        __syncthreads();
    }

    // MLP head + log_softmax, one thread per node (all data LDS-resident)
    if (tid < 64) {
        int node = node0 + tid;
        if (node < NN) {
            float a[64];
            #pragma unroll
            for (int k = 0; k < 64; ++k) a[k] = accS[tid * 65 + k];
            float h1[32];
            for (int j = 0; j < 32; ++j) {
                float s = b1s[j];
                #pragma unroll
                for (int k = 0; k < 64; ++k) s += a[k] * w1s[k * 32 + j];
                h1[j] = fmaxf(s, 0.f);
            }
            float h2[16];
            for (int j = 0; j < 16; ++j) {
                float s = b2s[j];
                #pragma unroll
                for (int k = 0; k < 32; ++k) s += h1[k] * w2s[k * 16 + j];
                h2[j] = fmaxf(s, 0.f);
            }
            float l[4];
            for (int c = 0; c < 4; ++c) {
                float s = b3s[c];
                #pragma unroll
                for (int k = 0; k < 16; ++k) s += h2[k] * w3s[k * 4 + c];
                l[c] = s;
            }
            float m = fmaxf(fmaxf(l[0], l[1]), fmaxf(l[2], l[3]));
            float sum = 0.f;
            #pragma unroll
            for (int c = 0; c < 4; ++c) sum += expf(l[c] - m);
            float lse = logf(sum);
            float4 o;
            o.x = l[0] - m - lse; o.y = l[1] - m - lse; o.z = l[2] - m - lse; o.w = l[3] - m - lse;
            *reinterpret_cast<float4*>(&out[(size_t)node * CC]) = o;
        }
    }
}

extern "C" void kernel_launch(void* const* d_in, const int* in_sizes, int n_in,
                              void* d_out, int out_size, void* d_ws, size_t ws_size,
                              hipStream_t stream) {
    const float* x    = (const float*)d_in[0];
    const int*  edges = (const int*)d_in[1];
    const float* Wg   = (const float*)d_in[2];
    const float* bg   = (const float*)d_in[3];
    const float* W1   = (const float*)d_in[4];
    const float* b1   = (const float*)d_in[5];
    const float* W2   = (const float*)d_in[6];
    const float* b2   = (const float*)d_in[7];
    const float* W3   = (const float*)d_in[8];
    const float* b3   = (const float*)d_in[9];
    float* out = (float*)d_out;

    char* ws = (char*)d_ws;
    size_t o = 0;
    int* cnt       = (int*)(ws + o); o += (size_t)TT * NN * 4;         // 1.6 MB
    float* dinv    = (float*)(ws + o); o += (size_t)TT * NN * 4;       // 1.6 MB
    int* bcnt      = (int*)(ws + o); o += (size_t)TT * NB * 4;         // 25 KB
    int* bucketOff = (int*)(ws + o); o += (size_t)TT * (NB + 1) * 4;   // 25 KB
    o = (o + 255) & ~(size_t)255;
    int* cursor    = (int*)(ws + o); o += (size_t)TT * NB * 4;         // 25 KB
    o = (o + 255) & ~(size_t)255;
    int* binned    = (int*)(ws + o); o += (size_t)TT * EE * 4;         // 25.6 MB
    u16* y         = (u16*)(ws + o); o += (size_t)TT * NN * HH * 2;    // 51.2 MB
    // total ~80 MB

    hipMemsetAsync(cnt, 0, (size_t)TT * NN * 4, stream);

    hist_kernel<<<3125 * TT, 256, 0, stream>>>(edges, cnt);

    dim3 gb((NB + 255) / 256, TT);
    bucket_cnt_kernel<<<gb, 256, 0, stream>>>(cnt, bcnt);
    bucket_scan_kernel<<<TT, 1024, 0, stream>>>(bcnt, bucketOff, cursor);

    bin_fill_kernel<<<3125 * TT, 256, 0, stream>>>(edges, cursor, binned);

    dim3 gx(782, TT);
    xw_kernel<<<gx, 256, 0, stream>>>(x, Wg, cnt, dinv, y);

    agg_fused_kernel<<<NB, 256, 0, stream>>>(y, dinv, bucketOff, binned, bg,
                                             W1, b1, W2, b2, W3, b3, out);
}

// Round 4
// 981.817 us; speedup vs baseline: 3.6456x; 3.6456x over previous
//
#include <hip/hip_runtime.h>

#define TT 8
#define NN 50000
#define FF 128
#define HH 64
#define CC 4
#define EE 800000
#define NB 782            // ceil(50000/64) buckets of 64 nodes

typedef unsigned short u16;

static __device__ __forceinline__ float bf2f(u16 u) {
    union { unsigned int i; float f; } v; v.i = ((unsigned int)u) << 16; return v.f;
}
static __device__ __forceinline__ u16 f2bf(float f) {
    union { float f; unsigned int u; } v; v.f = f;
    unsigned int u = v.u;
    unsigned int r = u + 0x7fffu + ((u >> 16) & 1u);   // round-to-nearest-even
    return (u16)(r >> 16);
}

// ---------------- histogram of edge destinations (in-degree, no self loop) ----------------
__global__ __launch_bounds__(256) void hist_kernel(const int* __restrict__ edges, int* __restrict__ cnt) {
    int bid = blockIdx.x;
    int t = bid & 7;
    int e = (bid >> 3) * 256 + threadIdx.x;
    if (e < EE) {
        int dst = edges[(t * 2 + 1) * EE + e];
        atomicAdd(&cnt[t * NN + dst], 1);
    }
}

// ---------------- 2-level exclusive scan over cnt -> offs ----------------
__global__ __launch_bounds__(256) void scan_partial_kernel(const int* __restrict__ cnt, int* __restrict__ partials) {
    int t = blockIdx.y, cb = blockIdx.x, tid = threadIdx.x;
    int i = cb * 256 + tid;
    int v = (i < NN) ? cnt[t * NN + i] : 0;
    __shared__ int s[256];
    s[tid] = v; __syncthreads();
    for (int off = 128; off > 0; off >>= 1) {
        if (tid < off) s[tid] += s[tid + off];
        __syncthreads();
    }
    if (tid == 0) partials[t * 200 + cb] = s[0];
}

__global__ __launch_bounds__(256) void scan_top_kernel(int* __restrict__ partials, int* __restrict__ offs) {
    int t = blockIdx.x, tid = threadIdx.x;
    __shared__ int s[256];
    int v = (tid < 196) ? partials[t * 200 + tid] : 0;
    s[tid] = v; __syncthreads();
    for (int off = 1; off < 256; off <<= 1) {
        int x = 0;
        if (tid >= off) x = s[tid - off];
        __syncthreads();
        s[tid] += x;
        __syncthreads();
    }
    if (tid < 196) partials[t * 200 + tid] = s[tid] - v;   // exclusive
    if (tid == 0) offs[t * (NN + 1) + NN] = EE;
}

// per-node exclusive offsets; also init the 782 bucket cursors (= offs at bucket starts)
__global__ __launch_bounds__(256) void scan_final_kernel(const int* __restrict__ cnt, const int* __restrict__ partials,
                                                         int* __restrict__ offs, int* __restrict__ bcursor) {
    int t = blockIdx.y, cb = blockIdx.x, tid = threadIdx.x;
    int i = cb * 256 + tid;
    int v = (i < NN) ? cnt[t * NN + i] : 0;
    __shared__ int s[256];
    s[tid] = v; __syncthreads();
    for (int off = 1; off < 256; off <<= 1) {
        int x = 0;
        if (tid >= off) x = s[tid - off];
        __syncthreads();
        s[tid] += x;
        __syncthreads();
    }
    int excl = s[tid] - v + partials[t * 200 + cb];
    if (i < NN) {
        offs[t * (NN + 1) + i] = excl;
        if ((i & 63) == 0) bcursor[t * NB + (i >> 6)] = excl;
    }
}

// ---------------- stage 1: bin edges into 64-node buckets (packed src|dstlo<<16) ----------------
// 782 append streams per t (XCD-pinned): active dirty-line set ~50KB -> lines fill fast,
// full-line writebacks (vs 50000-stream CSR fill: 478MB written for 25.6MB payload).
__global__ __launch_bounds__(256) void bin_fill_kernel(const int* __restrict__ edges, int* __restrict__ bcursor,
                                                       int* __restrict__ binned) {
    int bid = blockIdx.x;
    int t = bid & 7;
    int e = (bid >> 3) * 256 + threadIdx.x;
    if (e < EE) {
        int src = edges[(t * 2 + 0) * EE + e];
        int dst = edges[(t * 2 + 1) * EE + e];
        int b = dst >> 6;
        int p = atomicAdd(&bcursor[t * NB + b], 1);
        binned[(size_t)t * EE + p] = src | ((dst & 63) << 16);
    }
}

// ---------------- stage 2: per-bucket scatter to exact CSR position (u16 srclist) ----------------
// one block per (bucket,t); LDS cursors; writes land in the bucket's contiguous ~2KB window.
__global__ __launch_bounds__(256) void csr_scatter_kernel(const int* __restrict__ binned, const int* __restrict__ offs,
                                                          u16* __restrict__ srclist) {
    int b = blockIdx.x, t = blockIdx.y, tid = threadIdx.x;
    int node0 = b * 64;
    __shared__ int cur[64];
    if (tid < 64) {
        int idx = node0 + tid;
        cur[tid] = offs[t * (NN + 1) + (idx < NN ? idx : NN)];
    }
    __syncthreads();
    int beg = offs[t * (NN + 1) + node0];
    int hi = node0 + 64; if (hi > NN) hi = NN;
    int end = offs[t * (NN + 1) + hi];
    const int* bl = binned + (size_t)t * EE;
    u16* sl = srclist + (size_t)t * EE;
    for (int j = beg + tid; j < end; j += 256) {
        int rec = bl[j];
        int d = rec >> 16;
        int p = atomicAdd(&cur[d], 1);
        sl[p] = (u16)(rec & 0xFFFF);
    }
}

// ---------------- y = (x @ Wg) * dinv  (per timestep), stored bf16 ----------------
__global__ __launch_bounds__(256) void xw_kernel(const float* __restrict__ x, const float* __restrict__ Wg,
                                                 const int* __restrict__ cnt, float* __restrict__ dinv,
                                                 u16* __restrict__ y) {
    int t = blockIdx.y;
    int row0 = blockIdx.x * 64;
    int tid = threadIdx.x;
    __shared__ __align__(16) float xs[64 * 132];
    __shared__ float ds[64];
    const float* xt = x + (size_t)t * NN * FF;
    #pragma unroll
    for (int it = 0; it < 8; ++it) {
        int f = it * 256 + tid;          // float4 index: 64 rows x 32
        int r = f >> 5, k4 = f & 31;
        int row = row0 + r;
        float4 v = make_float4(0.f, 0.f, 0.f, 0.f);
        if (row < NN) v = *reinterpret_cast<const float4*>(&xt[(size_t)row * FF + k4 * 4]);
        *reinterpret_cast<float4*>(&xs[r * 132 + k4 * 4]) = v;
    }
    if (tid < 64) {
        int row = row0 + tid;
        float d = 0.f;
        if (row < NN) {
            d = rsqrtf(1.0f + (float)cnt[t * NN + row]);
            dinv[t * NN + row] = d;
        }
        ds[tid] = d;
    }
    __syncthreads();

    int c0 = (tid & 15) << 2;
    int r0 = (tid >> 4) << 2;
    const float* wgt = Wg + t * FF * HH;
    float s[4][4] = {};
    #pragma unroll 4
    for (int k0 = 0; k0 < 128; k0 += 4) {
        float4 xr[4], wr[4];
        #pragma unroll
        for (int j = 0; j < 4; ++j) xr[j] = *reinterpret_cast<const float4*>(&xs[(r0 + j) * 132 + k0]);
        #pragma unroll
        for (int j = 0; j < 4; ++j) wr[j] = *reinterpret_cast<const float4*>(&wgt[(k0 + j) * 64 + c0]);
        #pragma unroll
        for (int kk = 0; kk < 4; ++kk) {
            float wx = wr[kk].x, wy = wr[kk].y, wz = wr[kk].z, ww = wr[kk].w;
            #pragma unroll
            for (int r = 0; r < 4; ++r) {
                float xv = (kk == 0) ? xr[r].x : (kk == 1) ? xr[r].y : (kk == 2) ? xr[r].z : xr[r].w;
                s[r][0] += xv * wx;
                s[r][1] += xv * wy;
                s[r][2] += xv * wz;
                s[r][3] += xv * ww;
            }
        }
    }
    #pragma unroll
    for (int j = 0; j < 4; ++j) {
        int row = row0 + r0 + j;
        if (row < NN) {
            float dv = ds[r0 + j];
            ushort4 pk;
            pk.x = f2bf(s[j][0] * dv);
            pk.y = f2bf(s[j][1] * dv);
            pk.z = f2bf(s[j][2] * dv);
            pk.w = f2bf(s[j][3] * dv);
            *reinterpret_cast<ushort4*>(&y[((size_t)t * NN + row) * HH + c0]) = pk;
        }
    }
}

// ---------------- gather-aggregate over all T, relu-accumulate ----------------
// one wave per node; lane = feature column. 16 independent row-gathers in flight per wait.
__global__ __launch_bounds__(256) void agg_kernel(const u16* __restrict__ y, const float* __restrict__ dinv,
                                                  const int* __restrict__ offs, const u16* __restrict__ srclist,
                                                  const float* __restrict__ bg, float* __restrict__ acc) {
    int node = blockIdx.x * 4 + (threadIdx.x >> 6);
    int lane = threadIdx.x & 63;
    if (node >= NN) return;
    float a = 0.f;
    for (int t = 0; t < TT; ++t) {
        const u16* yt = y + (size_t)t * NN * HH;
        float s = bf2f(yt[(size_t)node * HH + lane]);   // self loop (y already scaled by dinv)
        int beg = offs[t * (NN + 1) + node];
        int end = offs[t * (NN + 1) + node + 1];
        const u16* sl = srclist + (size_t)t * EE;
        int j = beg;
        for (; j + 16 <= end; j += 16) {
            int idx[16];
            #pragma unroll
            for (int k = 0; k < 16; ++k) idx[k] = sl[j + k];
            float v[16];
            #pragma unroll
            for (int k = 0; k < 16; ++k) v[k] = bf2f(yt[(size_t)idx[k] * HH + lane]);
            float s0 = ((v[0] + v[1]) + (v[2] + v[3])) + ((v[4] + v[5]) + (v[6] + v[7]));
            float s1 = ((v[8] + v[9]) + (v[10] + v[11])) + ((v[12] + v[13]) + (v[14] + v[15]));
            s += s0 + s1;
        }
        if (j + 8 <= end) {
            int idx[8];
            #pragma unroll
            for (int k = 0; k < 8; ++k) idx[k] = sl[j + k];
            float v[8];
            #pragma unroll
            for (int k = 0; k < 8; ++k) v[k] = bf2f(yt[(size_t)idx[k] * HH + lane]);
            s += ((v[0] + v[1]) + (v[2] + v[3])) + ((v[4] + v[5]) + (v[6] + v[7]));
            j += 8;
        }
        if (j + 4 <= end) {
            int i0 = sl[j], i1 = sl[j + 1], i2 = sl[j + 2], i3 = sl[j + 3];
            float v0 = bf2f(yt[(size_t)i0 * HH + lane]);
            float v1 = bf2f(yt[(size_t)i1 * HH + lane]);
            float v2 = bf2f(yt[(size_t)i2 * HH + lane]);
            float v3 = bf2f(yt[(size_t)i3 * HH + lane]);
            s += (v0 + v1) + (v2 + v3);
            j += 4;
        }
        for (; j < end; ++j) s += bf2f(yt[(size_t)sl[j] * HH + lane]);
        float v = dinv[t * NN + node] * s + bg[t * HH + lane];
        a += fmaxf(v, 0.f);
    }
    acc[(size_t)node * HH + lane] = a;
}

// ---------------- per-node MLP head + log_softmax ----------------
__global__ __launch_bounds__(256) void head_kernel(const float* __restrict__ acc,
                                                   const float* __restrict__ W1, const float* __restrict__ b1,
                                                   const float* __restrict__ W2, const float* __restrict__ b2,
                                                   const float* __restrict__ W3, const float* __restrict__ b3,
                                                   float* __restrict__ out) {
    __shared__ float w1[64 * 32], w2[32 * 16], w3[16 * 4], bb1[32], bb2[16], bb3[4];
    int tid = threadIdx.x;
    for (int i = tid; i < 2048; i += 256) w1[i] = W1[i];
    for (int i = tid; i < 512; i += 256) w2[i] = W2[i];
    if (tid < 64) w3[tid] = W3[tid];
    if (tid < 32) bb1[tid] = b1[tid];
    if (tid < 16) bb2[tid] = b2[tid];
    if (tid < 4) bb3[tid] = b3[tid];
    __syncthreads();
    int node = blockIdx.x * 256 + tid;
    if (node >= NN) return;

    float a[64];
    #pragma unroll
    for (int k = 0; k < 64; ++k) a[k] = acc[(size_t)node * HH + k];

    float h1[32];
    for (int j = 0; j < 32; ++j) {
        float s = bb1[j];
        #pragma unroll
        for (int k = 0; k < 64; ++k) s += a[k] * w1[k * 32 + j];
        h1[j] = fmaxf(s, 0.f);
    }
    float h2[16];
    for (int j = 0; j < 16; ++j) {
        float s = bb2[j];
        #pragma unroll
        for (int k = 0; k < 32; ++k) s += h1[k] * w2[k * 16 + j];
        h2[j] = fmaxf(s, 0.f);
    }
    float l[4];
    for (int c = 0; c < 4; ++c) {
        float s = bb3[c];
        #pragma unroll
        for (int k = 0; k < 16; ++k) s += h2[k] * w3[k * 4 + c];
        l[c] = s;
    }
    float m = fmaxf(fmaxf(l[0], l[1]), fmaxf(l[2], l[3]));
    float sum = 0.f;
    #pragma unroll
    for (int c = 0; c < 4; ++c) sum += expf(l[c] - m);
    float lse = logf(sum);
    float4 o;
    o.x = l[0] - m - lse; o.y = l[1] - m - lse; o.z = l[2] - m - lse; o.w = l[3] - m - lse;
    *reinterpret_cast<float4*>(&out[(size_t)node * CC]) = o;
}

extern "C" void kernel_launch(void* const* d_in, const int* in_sizes, int n_in,
                              void* d_out, int out_size, void* d_ws, size_t ws_size,
                              hipStream_t stream) {
    const float* x    = (const float*)d_in[0];
    const int*  edges = (const int*)d_in[1];
    const float* Wg   = (const float*)d_in[2];
    const float* bg   = (const float*)d_in[3];
    const float* W1   = (const float*)d_in[4];
    const float* b1   = (const float*)d_in[5];
    const float* W2   = (const float*)d_in[6];
    const float* b2   = (const float*)d_in[7];
    const float* W3   = (const float*)d_in[8];
    const float* b3   = (const float*)d_in[9];
    float* out = (float*)d_out;

    char* ws = (char*)d_ws;
    size_t o = 0;
    int* cnt       = (int*)(ws + o); o += (size_t)TT * NN * 4;         // 1.6 MB
    float* dinv    = (float*)(ws + o); o += (size_t)TT * NN * 4;       // 1.6 MB
    int* offs      = (int*)(ws + o); o += (size_t)TT * (NN + 1) * 4;   // 1.6 MB
    int* partials  = (int*)(ws + o); o += (size_t)TT * 200 * 4;        // 6.4 KB
    o = (o + 255) & ~(size_t)255;
    int* bcursor   = (int*)(ws + o); o += (size_t)TT * NB * 4;         // 25 KB
    o = (o + 255) & ~(size_t)255;
    int* binned    = (int*)(ws + o); o += (size_t)TT * EE * 4;         // 25.6 MB
    u16* srclist   = (u16*)(ws + o); o += (size_t)TT * EE * 2;         // 12.8 MB
    u16* y         = (u16*)(ws + o); o += (size_t)TT * NN * HH * 2;    // 51.2 MB
    float* acc     = (float*)(ws + o); o += (size_t)NN * HH * 4;       // 12.8 MB
    // total ~107 MB

    hipMemsetAsync(cnt, 0, (size_t)TT * NN * 4, stream);

    hist_kernel<<<3125 * TT, 256, 0, stream>>>(edges, cnt);

    dim3 gs(196, TT);
    scan_partial_kernel<<<gs, 256, 0, stream>>>(cnt, partials);
    scan_top_kernel<<<TT, 256, 0, stream>>>(partials, offs);
    scan_final_kernel<<<gs, 256, 0, stream>>>(cnt, partials, offs, bcursor);

    bin_fill_kernel<<<3125 * TT, 256, 0, stream>>>(edges, bcursor, binned);

    dim3 gsc(NB, TT);
    csr_scatter_kernel<<<gsc, 256, 0, stream>>>(binned, offs, srclist);

    dim3 gx(782, TT);
    xw_kernel<<<gx, 256, 0, stream>>>(x, Wg, cnt, dinv, y);

    agg_kernel<<<12500, 256, 0, stream>>>(y, dinv, offs, srclist, bg, acc);

    head_kernel<<<196, 256, 0, stream>>>(acc, W1, b1, W2, b2, W3, b3, out);
}

// Round 5
// 461.898 us; speedup vs baseline: 7.7491x; 2.1256x over previous
//
#include <hip/hip_runtime.h>

#define TT 8
#define NN 50000
#define FF 128
#define HH 64
#define CC 4
#define EE 800000
#define NB2 391           // buckets of 128 nodes (ceil(50000/128))
#define CAP 2560          // padded records per (t,bucket): mean 2048, sd ~45 -> 11 sigma
#define BPT 64            // multisplit blocks per timestep

typedef unsigned short u16;
typedef unsigned int u32;

static __device__ __forceinline__ float bf2f(u16 u) {
    union { unsigned int i; float f; } v; v.i = ((unsigned int)u) << 16; return v.f;
}
static __device__ __forceinline__ u16 f2bf(float f) {
    union { float f; unsigned int u; } v; v.f = f;
    unsigned int u = v.u;
    unsigned int r = u + 0x7fffu + ((u >> 16) & 1u);   // round-to-nearest-even
    return (u16)(r >> 16);
}

// ---------------- multisplit: edges -> 64B-aligned padded bucket windows ----------------
// LDS-staged: each bucket has a 16-record (64B) line buffer; only FULL ALIGNED LINES are
// flushed to global (fixes the 183MB-written-for-25.6MB scatter: 4B scattered stores never
// combine before leaving L2; 64B aligned block stores are amplification-free by construction).
__global__ __launch_bounds__(256) void multisplit_kernel(const int* __restrict__ edges,
                                                         int* __restrict__ gcur, u32* __restrict__ binned) {
    __shared__ u32 sbuf[NB2][16];
    __shared__ int scnt[NB2];
    int bid = blockIdx.x;
    int t = bid & 7;
    int blk = bid >> 3;                       // 0..BPT-1
    const int per = (EE + BPT - 1) / BPT;     // 12500
    int e0 = blk * per;
    int e1 = e0 + per; if (e1 > EE) e1 = EE;

    for (int i = threadIdx.x; i < NB2; i += 256) scnt[i] = 0;
    __syncthreads();

    const int* es = edges + (size_t)(t * 2 + 0) * EE;
    const int* ed = edges + (size_t)(t * 2 + 1) * EE;
    int* gc = gcur + t * NB2;
    u32* bb = binned + (size_t)t * NB2 * CAP;

    for (int base = e0; base < e1; base += 256) {
        int e = base + threadIdx.x;
        u32 rec = 0; int b = -1;
        if (e < e1) {
            int src = es[e], dst = ed[e];
            b = dst >> 7;
            rec = (u32)src | ((u32)(dst & 127) << 16);
            int p = atomicAdd(&scnt[b], 1);
            if (p < 16) { sbuf[b][p] = rec; b = -1; }    // stored; else pending
        }
        __syncthreads();
        // flush any full 64B line
        for (int fb = threadIdx.x; fb < NB2; fb += 256) {
            if (scnt[fb] >= 16) {
                int g = atomicAdd(&gc[fb], 16);
                uint4* dp = (uint4*)(bb + (size_t)fb * CAP + g);
                uint4* sp = (uint4*)&sbuf[fb][0];
                dp[0] = sp[0]; dp[1] = sp[1]; dp[2] = sp[2]; dp[3] = sp[3];
                scnt[fb] = 0;                            // pendings re-append below
            }
        }
        __syncthreads();
        if (b >= 0) {                                    // pending retry (count was >16)
            int p = atomicAdd(&scnt[b], 1);
            if (p < 16) sbuf[b][p] = rec;
            else { int g = atomicAdd(&gc[b], 1); bb[(size_t)b * CAP + g] = rec; }  // ultra-rare
        }
        __syncthreads();
    }
    // residual (<16 per bucket) partial flush
    for (int fb = threadIdx.x; fb < NB2; fb += 256) {
        int c = scnt[fb];
        if (c > 0) {
            int g = atomicAdd(&gc[fb], c);
            for (int k = 0; k < c; ++k) bb[(size_t)fb * CAP + g + k] = sbuf[fb][k];
        }
    }
}

// ---------------- per-bucket: local degree hist + scan -> CSR scatter + nodeinfo + dinv ----------------
// one block per (bucket,t): stage ~2048 records in LDS, histogram 128 node counters, local
// exclusive scan, scatter u16 srclist into the bucket's padded window, emit packed
// nodeinfo = beg | deg<<20 and dinv = rsqrt(1+deg). Replaces hist + 3 scan kernels.
__global__ __launch_bounds__(256) void csr_scatter_kernel(const u32* __restrict__ binned, const int* __restrict__ gcur,
                                                          u16* __restrict__ srclist, u32* __restrict__ nodeinfo,
                                                          float* __restrict__ dinv) {
    __shared__ u32 recs[CAP];
    __shared__ int hist[128];
    __shared__ int cur[128];
    int b = blockIdx.x, t = blockIdx.y, tid = threadIdx.x;
    int node0 = b * 128;
    int tot = gcur[t * NB2 + b];
    const u32* win = binned + ((size_t)t * NB2 + b) * CAP;

    for (int i = tid; i < tot; i += 256) recs[i] = win[i];
    if (tid < 128) hist[tid] = 0;
    __syncthreads();
    for (int i = tid; i < tot; i += 256) atomicAdd(&hist[recs[i] >> 16], 1);
    __syncthreads();
    int h = 0;
    if (tid < 128) h = hist[tid];
    for (int off = 1; off < 128; off <<= 1) {
        int v = 0;
        if (tid < 128 && tid >= off) v = hist[tid - off];
        __syncthreads();
        if (tid < 128) hist[tid] += v;
        __syncthreads();
    }
    if (tid < 128) {
        int excl = hist[tid] - h;
        cur[tid] = excl;
        int node = node0 + tid;
        if (node < NN) {
            nodeinfo[t * NN + node] = (u32)(b * CAP + excl) | ((u32)h << 20);
            dinv[t * NN + node] = rsqrtf(1.0f + (float)h);
        }
    }
    __syncthreads();
    u16* sl = srclist + (size_t)t * NB2 * CAP;
    for (int i = tid; i < tot; i += 256) {
        u32 rec = recs[i];
        int d = rec >> 16;
        int p = atomicAdd(&cur[d], 1);
        sl[(size_t)b * CAP + p] = (u16)(rec & 0xFFFF);
    }
}

// ---------------- y = (x @ Wg) * dinv  (per timestep), stored bf16 ----------------
__global__ __launch_bounds__(256) void xw_kernel(const float* __restrict__ x, const float* __restrict__ Wg,
                                                 const float* __restrict__ dinv, u16* __restrict__ y) {
    int t = blockIdx.y;
    int row0 = blockIdx.x * 64;
    int tid = threadIdx.x;
    __shared__ __align__(16) float xs[64 * 132];
    __shared__ float ds[64];
    const float* xt = x + (size_t)t * NN * FF;
    #pragma unroll
    for (int it = 0; it < 8; ++it) {
        int f = it * 256 + tid;          // float4 index: 64 rows x 32
        int r = f >> 5, k4 = f & 31;
        int row = row0 + r;
        float4 v = make_float4(0.f, 0.f, 0.f, 0.f);
        if (row < NN) v = *reinterpret_cast<const float4*>(&xt[(size_t)row * FF + k4 * 4]);
        *reinterpret_cast<float4*>(&xs[r * 132 + k4 * 4]) = v;
    }
    if (tid < 64) {
        int row = row0 + tid;
        ds[tid] = (row < NN) ? dinv[t * NN + row] : 0.f;
    }
    __syncthreads();

    int c0 = (tid & 15) << 2;
    int r0 = (tid >> 4) << 2;
    const float* wgt = Wg + t * FF * HH;
    float s[4][4] = {};
    #pragma unroll 4
    for (int k0 = 0; k0 < 128; k0 += 4) {
        float4 xr[4], wr[4];
        #pragma unroll
        for (int j = 0; j < 4; ++j) xr[j] = *reinterpret_cast<const float4*>(&xs[(r0 + j) * 132 + k0]);
        #pragma unroll
        for (int j = 0; j < 4; ++j) wr[j] = *reinterpret_cast<const float4*>(&wgt[(k0 + j) * 64 + c0]);
        #pragma unroll
        for (int kk = 0; kk < 4; ++kk) {
            float wx = wr[kk].x, wy = wr[kk].y, wz = wr[kk].z, ww = wr[kk].w;
            #pragma unroll
            for (int r = 0; r < 4; ++r) {
                float xv = (kk == 0) ? xr[r].x : (kk == 1) ? xr[r].y : (kk == 2) ? xr[r].z : xr[r].w;
                s[r][0] += xv * wx;
                s[r][1] += xv * wy;
                s[r][2] += xv * wz;
                s[r][3] += xv * ww;
            }
        }
    }
    #pragma unroll
    for (int j = 0; j < 4; ++j) {
        int row = row0 + r0 + j;
        if (row < NN) {
            float dv = ds[r0 + j];
            ushort4 pk;
            pk.x = f2bf(s[j][0] * dv);
            pk.y = f2bf(s[j][1] * dv);
            pk.z = f2bf(s[j][2] * dv);
            pk.w = f2bf(s[j][3] * dv);
            *reinterpret_cast<ushort4*>(&y[((size_t)t * NN + row) * HH + c0]) = pk;
        }
    }
}

// ---------------- gather-aggregate over all T, relu-accumulate ----------------
// one wave per node; lane = feature column. 16 independent row-gathers in flight per wait.
__global__ __launch_bounds__(256) void agg_kernel(const u16* __restrict__ y, const float* __restrict__ dinv,
                                                  const u32* __restrict__ nodeinfo, const u16* __restrict__ srclist,
                                                  const float* __restrict__ bg, float* __restrict__ acc) {
    int node = blockIdx.x * 4 + (threadIdx.x >> 6);
    int lane = threadIdx.x & 63;
    if (node >= NN) return;
    float a = 0.f;
    for (int t = 0; t < TT; ++t) {
        const u16* yt = y + (size_t)t * NN * HH;
        float s = bf2f(yt[(size_t)node * HH + lane]);   // self loop (y already scaled by dinv)
        u32 info = nodeinfo[t * NN + node];
        int cnt = info >> 20;
        const u16* sl = srclist + (size_t)t * NB2 * CAP + (info & 0xFFFFF);
        int j = 0;
        for (; j + 16 <= cnt; j += 16) {
            int idx[16];
            #pragma unroll
            for (int k = 0; k < 16; ++k) idx[k] = sl[j + k];
            float v[16];
            #pragma unroll
            for (int k = 0; k < 16; ++k) v[k] = bf2f(yt[(size_t)idx[k] * HH + lane]);
            float s0 = ((v[0] + v[1]) + (v[2] + v[3])) + ((v[4] + v[5]) + (v[6] + v[7]));
            float s1 = ((v[8] + v[9]) + (v[10] + v[11])) + ((v[12] + v[13]) + (v[14] + v[15]));
            s += s0 + s1;
        }
        if (j + 8 <= cnt) {
            int idx[8];
            #pragma unroll
            for (int k = 0; k < 8; ++k) idx[k] = sl[j + k];
            float v[8];
            #pragma unroll
            for (int k = 0; k < 8; ++k) v[k] = bf2f(yt[(size_t)idx[k] * HH + lane]);
            s += ((v[0] + v[1]) + (v[2] + v[3])) + ((v[4] + v[5]) + (v[6] + v[7]));
            j += 8;
        }
        if (j + 4 <= cnt) {
            int i0 = sl[j], i1 = sl[j + 1], i2 = sl[j + 2], i3 = sl[j + 3];
            float v0 = bf2f(yt[(size_t)i0 * HH + lane]);
            float v1 = bf2f(yt[(size_t)i1 * HH + lane]);
            float v2 = bf2f(yt[(size_t)i2 * HH + lane]);
            float v3 = bf2f(yt[(size_t)i3 * HH + lane]);
            s += (v0 + v1) + (v2 + v3);
            j += 4;
        }
        for (; j < cnt; ++j) s += bf2f(yt[(size_t)sl[j] * HH + lane]);
        float v = dinv[t * NN + node] * s + bg[t * HH + lane];
        a += fmaxf(v, 0.f);
    }
    acc[(size_t)node * HH + lane] = a;
}

// ---------------- per-node MLP head + log_softmax ----------------
__global__ __launch_bounds__(256) void head_kernel(const float* __restrict__ acc,
                                                   const float* __restrict__ W1, const float* __restrict__ b1,
                                                   const float* __restrict__ W2, const float* __restrict__ b2,
                                                   const float* __restrict__ W3, const float* __restrict__ b3,
                                                   float* __restrict__ out) {
    __shared__ float w1[64 * 32], w2[32 * 16], w3[16 * 4], bb1[32], bb2[16], bb3[4];
    int tid = threadIdx.x;
    for (int i = tid; i < 2048; i += 256) w1[i] = W1[i];
    for (int i = tid; i < 512; i += 256) w2[i] = W2[i];
    if (tid < 64) w3[tid] = W3[tid];
    if (tid < 32) bb1[tid] = b1[tid];
    if (tid < 16) bb2[tid] = b2[tid];
    if (tid < 4) bb3[tid] = b3[tid];
    __syncthreads();
    int node = blockIdx.x * 256 + tid;
    if (node >= NN) return;

    float a[64];
    #pragma unroll
    for (int k = 0; k < 64; ++k) a[k] = acc[(size_t)node * HH + k];

    float h1[32];
    for (int j = 0; j < 32; ++j) {
        float s = bb1[j];
        #pragma unroll
        for (int k = 0; k < 64; ++k) s += a[k] * w1[k * 32 + j];
        h1[j] = fmaxf(s, 0.f);
    }
    float h2[16];
    for (int j = 0; j < 16; ++j) {
        float s = bb2[j];
        #pragma unroll
        for (int k = 0; k < 32; ++k) s += h1[k] * w2[k * 16 + j];
        h2[j] = fmaxf(s, 0.f);
    }
    float l[4];
    for (int c = 0; c < 4; ++c) {
        float s = bb3[c];
        #pragma unroll
        for (int k = 0; k < 16; ++k) s += h2[k] * w3[k * 4 + c];
        l[c] = s;
    }
    float m = fmaxf(fmaxf(l[0], l[1]), fmaxf(l[2], l[3]));
    float sum = 0.f;
    #pragma unroll
    for (int c = 0; c < 4; ++c) sum += expf(l[c] - m);
    float lse = logf(sum);
    float4 o;
    o.x = l[0] - m - lse; o.y = l[1] - m - lse; o.z = l[2] - m - lse; o.w = l[3] - m - lse;
    *reinterpret_cast<float4*>(&out[(size_t)node * CC]) = o;
}

extern "C" void kernel_launch(void* const* d_in, const int* in_sizes, int n_in,
                              void* d_out, int out_size, void* d_ws, size_t ws_size,
                              hipStream_t stream) {
    const float* x    = (const float*)d_in[0];
    const int*  edges = (const int*)d_in[1];
    const float* Wg   = (const float*)d_in[2];
    const float* bg   = (const float*)d_in[3];
    const float* W1   = (const float*)d_in[4];
    const float* b1   = (const float*)d_in[5];
    const float* W2   = (const float*)d_in[6];
    const float* b2   = (const float*)d_in[7];
    const float* W3   = (const float*)d_in[8];
    const float* b3   = (const float*)d_in[9];
    float* out = (float*)d_out;

    char* ws = (char*)d_ws;
    size_t o = 0;
    int* gcur      = (int*)(ws + o); o += (size_t)TT * NB2 * 4;            // 12.5 KB
    o = (o + 255) & ~(size_t)255;
    float* dinv    = (float*)(ws + o); o += (size_t)TT * NN * 4;           // 1.6 MB
    u32* nodeinfo  = (u32*)(ws + o); o += (size_t)TT * NN * 4;             // 1.6 MB
    o = (o + 255) & ~(size_t)255;
    u32* binned    = (u32*)(ws + o); o += (size_t)TT * NB2 * CAP * 4;      // 32.0 MB
    u16* srclist   = (u16*)(ws + o); o += (size_t)TT * NB2 * CAP * 2;      // 16.0 MB
    u16* y         = (u16*)(ws + o); o += (size_t)TT * NN * HH * 2;        // 51.2 MB
    float* acc     = (float*)(ws + o); o += (size_t)NN * HH * 4;           // 12.8 MB
    // total ~115 MB

    hipMemsetAsync(gcur, 0, (size_t)TT * NB2 * 4, stream);

    multisplit_kernel<<<BPT * TT, 256, 0, stream>>>(edges, gcur, binned);

    dim3 gsc(NB2, TT);
    csr_scatter_kernel<<<gsc, 256, 0, stream>>>(binned, gcur, srclist, nodeinfo, dinv);

    dim3 gx(782, TT);
    xw_kernel<<<gx, 256, 0, stream>>>(x, Wg, dinv, y);

    agg_kernel<<<12500, 256, 0, stream>>>(y, dinv, nodeinfo, srclist, bg, acc);

    head_kernel<<<196, 256, 0, stream>>>(acc, W1, b1, W2, b2, W3, b3, out);
}